// Round 6
// baseline (317.205 us; speedup 1.0000x reference)
//
#include <hip/hip_runtime.h>
#include <hip/hip_bf16.h>

#define BB 4
#define SS 2048
#define EE 1024
#define HH 512

typedef __attribute__((ext_vector_type(8))) short short8;
typedef __attribute__((ext_vector_type(4))) float f32x4;

static __device__ __forceinline__ unsigned short f2bf(float x){
  unsigned u = __float_as_uint(x);
  u += 0x7fffu + ((u >> 16) & 1u);
  return (unsigned short)(u >> 16);
}

static __device__ __forceinline__ void gload16(const void* g, void* l){
  __builtin_amdgcn_global_load_lds((const __attribute__((address_space(1))) void*)g,
                                   (__attribute__((address_space(3))) void*)l, 16, 0, 0);
}

#define LGKM0 asm volatile("s_waitcnt lgkmcnt(0)" ::: "memory")
#define VM0   asm volatile("s_waitcnt vmcnt(0)"   ::: "memory")
#define SBAR  do { __builtin_amdgcn_sched_barrier(0); __builtin_amdgcn_s_barrier(); \
                   __builtin_amdgcn_sched_barrier(0); } while(0)

// ---------------- fp32 -> bf16 conversion (vectorized, grid-stride) ----------------
__global__ void k_cvt(const float* __restrict__ in, unsigned short* __restrict__ out, int n8){
  int idx = blockIdx.x * blockDim.x + threadIdx.x;
  int stride = gridDim.x * blockDim.x;
  for (int i = idx; i < n8; i += stride){
    const float4* p = (const float4*)in + (long)i * 2;
    float4 a = p[0], b = p[1];
    union { unsigned short u[8]; uint4 v; } r;
    r.u[0]=f2bf(a.x); r.u[1]=f2bf(a.y); r.u[2]=f2bf(a.z); r.u[3]=f2bf(a.w);
    r.u[4]=f2bf(b.x); r.u[5]=f2bf(b.y); r.u[6]=f2bf(b.z); r.u[7]=f2bf(b.w);
    ((uint4*)out)[i] = r.v;
  }
}

// ---------------- MFMA GEMM: C[M,N] = (A[M,K] * B^T + bias) * oscale ----------------
#define GBK 32

template<bool OUT_BF16>
static __device__ __forceinline__ void gemm_tile(
    const unsigned short* __restrict__ A, int lda,
    const unsigned short* __restrict__ Bw, int ldb,
    void* __restrict__ Cc, int ldc,
    const float* __restrict__ bias, int K, int row0, int col0, float oscale)
{
  __shared__ unsigned short As[2][128 * GBK];
  __shared__ unsigned short Bs[2][128 * GBK];
  const int tid = threadIdx.x, lane = tid & 63, w = tid >> 6;
  const int wm = w >> 1, wn = w & 1;
  const int fr = lane & 15, g = lane >> 4;

  f32x4 acc[4][4];
  #pragma unroll
  for (int i = 0; i < 4; i++)
    #pragma unroll
    for (int j = 0; j < 4; j++){ acc[i][j][0]=0.f; acc[i][j][1]=0.f; acc[i][j][2]=0.f; acc[i][j][3]=0.f; }

  const unsigned short* gAsrc[2]; const unsigned short* gBsrc[2];
  unsigned ldsOff[2];
  #pragma unroll
  for (int i = 0; i < 2; i++){
    int slot = w*128 + i*64 + lane;
    int row = slot >> 2, ch = slot & 3;
    int sc_ = ch ^ ((row >> 1) & 3);
    gAsrc[i] = A  + (long)(row0 + row) * lda + sc_ * 8;
    gBsrc[i] = Bw + (long)(col0 + row) * ldb + sc_ * 8;
    ldsOff[i] = (unsigned)((w*128 + i*64) * 8);
  }

  unsigned aoff[4], boff[4];
  #pragma unroll
  for (int mi = 0; mi < 4; mi++){
    int row = wm*64 + mi*16 + fr;
    aoff[mi] = row * GBK + ((g ^ ((row >> 1) & 3)) * 8);
  }
  #pragma unroll
  for (int ni = 0; ni < 4; ni++){
    int row = wn*64 + ni*16 + fr;
    boff[ni] = row * GBK + ((g ^ ((row >> 1) & 3)) * 8);
  }

  const int KT = K / GBK;
  #pragma unroll
  for (int i = 0; i < 2; i++) gload16(gAsrc[i], &As[0][ldsOff[i]]);
  #pragma unroll
  for (int i = 0; i < 2; i++) gload16(gBsrc[i], &Bs[0][ldsOff[i]]);
  __syncthreads();

  for (int kt = 0; kt < KT; ++kt){
    const int cur = kt & 1;
    if (kt + 1 < KT){
      #pragma unroll
      for (int i = 0; i < 2; i++) gload16(gAsrc[i] + (kt+1)*GBK, &As[cur^1][ldsOff[i]]);
      #pragma unroll
      for (int i = 0; i < 2; i++) gload16(gBsrc[i] + (kt+1)*GBK, &Bs[cur^1][ldsOff[i]]);
    }
    short8 av[4], bv[4];
    #pragma unroll
    for (int mi = 0; mi < 4; mi++) av[mi] = *(const short8*)&As[cur][aoff[mi]];
    #pragma unroll
    for (int ni = 0; ni < 4; ni++) bv[ni] = *(const short8*)&Bs[cur][boff[ni]];
    #pragma unroll
    for (int mi = 0; mi < 4; mi++)
      #pragma unroll
      for (int ni = 0; ni < 4; ni++)
        acc[mi][ni] = __builtin_amdgcn_mfma_f32_16x16x32_bf16(av[mi], bv[ni], acc[mi][ni], 0, 0, 0);
    __syncthreads();
  }

  #pragma unroll
  for (int mi = 0; mi < 4; mi++){
    #pragma unroll
    for (int ni = 0; ni < 4; ni++){
      int row = row0 + wm*64 + mi*16 + g*4;
      int col = col0 + wn*64 + ni*16 + fr;
      float bb = bias[col];
      #pragma unroll
      for (int r = 0; r < 4; r++){
        float v = (acc[mi][ni][r] + bb) * oscale;
        if (OUT_BF16) ((unsigned short*)Cc)[(long)(row + r) * ldc + col] = f2bf(v);
        else          ((float*)Cc)[(long)(row + r) * ldc + col] = v;
      }
    }
  }
}

__global__ __launch_bounds__(256, 2) void k_qkv(
    const unsigned short* __restrict__ xb,
    const unsigned short* __restrict__ wq, const unsigned short* __restrict__ wk,
    const unsigned short* __restrict__ wv,
    const float* __restrict__ bq, const float* __restrict__ bk, const float* __restrict__ bv,
    unsigned short* __restrict__ Q, unsigned short* __restrict__ K, unsigned short* __restrict__ V)
{
  int z = blockIdx.z; int which = z >> 3; int bn = z & 7; int b = bn >> 1, n = bn & 1;
  const unsigned short* W; const float* bias; unsigned short* out;
  float os = 1.f;
  if (which == 0){ W = wq; bias = bq; out = Q; os = 0.044194173824159216f; }  // fold 1/sqrt(512)
  else if (which == 1){ W = wk; bias = bk; out = K; }
  else { W = wv; bias = bv; out = V; }
  W += n * HH * HH; bias += n * HH; out += (long)bn * SS * HH;
  const unsigned short* Ap = xb + (long)b * SS * EE + n * HH;
  gemm_tile<true>(Ap, EE, W, HH, out, HH, bias, HH, blockIdx.x * 128, blockIdx.y * 128, os);
}

__global__ __launch_bounds__(256, 2) void k_outproj(
    const unsigned short* __restrict__ O, const unsigned short* __restrict__ wf,
    const float* __restrict__ bfb, float* __restrict__ out)
{
  gemm_tile<false>(O, EE, wf, EE, out, EE, bfb, EE, blockIdx.x * 128, blockIdx.y * 128, 1.f);
}

// ---------------- V [bn][s][o] -> Vt [bn][o][s] ----------------
__global__ __launch_bounds__(256) void k_transpose(const unsigned short* __restrict__ V,
                                                   unsigned short* __restrict__ Vt){
  __shared__ unsigned short t[64 * 64];
  long base = (long)blockIdx.z * SS * HH;
  const unsigned short* in = V + base;
  unsigned short* out = Vt + base;
  int s0 = blockIdx.x * 64, o0 = blockIdx.y * 64;
  int tid = threadIdx.x;
  int r = tid >> 3, cch = tid & 7;
  #pragma unroll
  for (int p = 0; p < 2; p++){
    int s = p * 32 + r;
    uint4 v = *(const uint4*)&in[(long)(s0 + s) * HH + o0 + cch * 8];
    *(uint4*)&t[s * 64 + ((cch ^ ((s >> 3) & 7)) * 8)] = v;
  }
  __syncthreads();
  #pragma unroll
  for (int p = 0; p < 2; p++){
    int o = p * 32 + r;
    union { unsigned short u[8]; uint4 v; } x;
    #pragma unroll
    for (int j = 0; j < 8; j++){
      int s = cch * 8 + j;
      x.u[j] = t[s * 64 + (((o >> 3) ^ ((s >> 3) & 7)) * 8) + (o & 7)];
    }
    *(uint4*)&out[(long)(o0 + o) * SS + s0 + cch * 8] = x.v;
  }
}

// ---------------- flash attention v6: counted-drain barriers + role-split staging ----------
// R5 math, new schedule. 8 waves, QB=128; waves 0-3 stage K only, 4-7 stage V only.
// Raw s_barrier; each wave drains vmcnt(0) only at the barrier publishing ITS buffer:
//   B2 (pre-PV):  V-waves drain (V(t) issued end of t-1)  | K-waves cross with K(t+1) in flight
//   B1 (tile end): K-waves drain (K(t+1) issued mid-t)    | V-waves cross with V(t+1) in flight
// All waves drain lgkmcnt(0) at both (publishes Ps/Al/Fls). Rescale gated block-wide (T13).
// setprio(1) around MFMA clusters (T5). CH=22 -> exactly 256 blocks, makespan 22 tiles.
#define QB 128
#define TB 32

__global__ __launch_bounds__(512, 1) void k_flash6(
    const unsigned short* __restrict__ Qg, const unsigned short* __restrict__ Kg,
    const unsigned short* __restrict__ Vtg,
    unsigned short* __restrict__ Opart, float* __restrict__ mlg,
    const int* __restrict__ maskedp)
{
  __shared__ unsigned short Ks[2][TB * HH];   // [t-row][k], chunk-swizzled: ch ^ (row&7)
  __shared__ unsigned short Vs[2][HH * TB];   // [h-row][t], chunk-swizzled: ch ^ ((row>>1)&3)
  __shared__ unsigned short Ps[8][16][TB + 8];
  __shared__ float Al[8][16];
  __shared__ int Fls[8];

  const int bid = blockIdx.x;
  const int bn = bid & 7;                     // XCD pinning
  const int u = bid >> 3;
  const int masked = *maskedp;
  int qi, c;
  if (masked){
    qi = -1; c = 0;
    int cnt = 0;
    #pragma unroll 1
    for (int q = 0; q < 16; q++){
      int nch = (4*q + 25) / 22;              // ceil((4q+4)/22)
      if (qi < 0 && u >= cnt && u < cnt + nch){ qi = q; c = u - cnt; }
      cnt += nch;
    }
    if (qi < 0) return;                       // safety (sum == 32, never hit)
  } else { qi = u >> 1; c = u & 1; }
  const int n  = masked ? 4*qi + 4 : 64;
  const int CH = masked ? 22 : 32;
  const int t0 = c * CH;
  const int t1 = min(n, t0 + CH);

  const long base = (long)bn * SS * HH;
  const unsigned short* Qp = Qg + base;
  const unsigned short* Kp = Kg + base;
  const unsigned short* Vp = Vtg + base;

  const int tid = threadIdx.x, lane = tid & 63, w = tid >> 6;
  const int fr = lane & 15, g = lane >> 4;
  const int q0 = qi * QB;
  const bool isK = (w < 4);

  // Q fragments: rows w*16+fr, full K
  short8 Qr[16];
  {
    const unsigned short* qrow = Qp + (long)(q0 + w * 16 + fr) * HH + g * 8;
    #pragma unroll
    for (int kk = 0; kk < 16; kk++) Qr[kk] = *(const short8*)(qrow + kk * 32);
  }

  // PV accumulator: O[rw*16..+16][w*64..+64]
  f32x4 Oacc[8][4];
  #pragma unroll
  for (int i = 0; i < 8; i++)
    #pragma unroll
    for (int j = 0; j < 4; j++){ Oacc[i][j][0]=0.f; Oacc[i][j][1]=0.f; Oacc[i][j][2]=0.f; Oacc[i][j][3]=0.f; }
  float m_r[4], l_r[4];
  #pragma unroll
  for (int r = 0; r < 4; r++){ m_r[r] = -1e30f; l_r[r] = 0.f; }

  auto stageK = [&](int buf, int t){          // waves 0-3: K tile, 8 gloads
    #pragma unroll
    for (int i = 0; i < 8; i++){
      const int sbase = w * 512 + i * 64;
      const int slot = sbase + lane;
      int row = slot >> 6, ch = slot & 63;
      int sc_ = ch ^ (row & 7);
      gload16(Kp + (long)(t * TB + row) * HH + sc_ * 8, &Ks[buf][sbase * 8]);
    }
  };
  auto stageV = [&](int buf, int t){          // waves 4-7: V^T tile, 8 gloads
    #pragma unroll
    for (int i = 0; i < 8; i++){
      const int sbase = (w - 4) * 512 + i * 64;
      const int slot = sbase + lane;
      int row = slot >> 2, ch = slot & 3;
      int sc_ = ch ^ ((row >> 1) & 3);
      gload16(Vp + (long)row * SS + t * TB + sc_ * 8, &Vs[buf][sbase * 8]);
    }
  };

  if (isK) stageK(0, t0); else stageV(0, t0);
  VM0; LGKM0; SBAR;                            // B0: both tiles visible

  for (int t = t0; t < t1; ++t){
    const int cur = (t - t0) & 1;

    // ---- QK^T: S[16 rows][32 t] ----
    f32x4 sc[2];
    #pragma unroll
    for (int tf = 0; tf < 2; tf++){ sc[tf][0]=0.f; sc[tf][1]=0.f; sc[tf][2]=0.f; sc[tf][3]=0.f; }
    __builtin_amdgcn_s_setprio(1);
    #pragma unroll
    for (int kk = 0; kk < 16; kk++){
      #pragma unroll
      for (int tf = 0; tf < 2; tf++){
        int row = tf * 16 + fr;
        short8 kf = *(const short8*)&Ks[cur][row * HH + (((kk * 4 + g) ^ (row & 7)) * 8)];
        sc[tf] = __builtin_amdgcn_mfma_f32_16x16x32_bf16(Qr[kk], kf, sc[tf], 0, 0, 0);
      }
    }
    __builtin_amdgcn_s_setprio(0);

    // K-waves: issue next K tile now (drained at B1, a full half-tile away)
    if (t + 1 < t1 && isK) stageK(cur ^ 1, t + 1);

    // ---- mask ----
    const bool needmask = masked && (t * TB + TB - 1 > q0 + w * 16);
    if (needmask){
      #pragma unroll
      for (int tf = 0; tf < 2; tf++){
        int col = t * TB + tf * 16 + fr;
        #pragma unroll
        for (int r = 0; r < 4; r++){
          int row = q0 + w * 16 + g * 4 + r;
          if (col > row) sc[tf][r] = -1e30f;
        }
      }
    }

    // ---- softmax ----
    float mx[4];
    #pragma unroll
    for (int r = 0; r < 4; r++) mx[r] = fmaxf(sc[0][r], sc[1][r]);
    #pragma unroll
    for (int d = 1; d < 16; d <<= 1){
      #pragma unroll
      for (int r = 0; r < 4; r++) mx[r] = fmaxf(mx[r], __shfl_xor(mx[r], d, 64));
    }
    float alpha[4];
    bool grow = false;
    #pragma unroll
    for (int r = 0; r < 4; r++) grow = grow || (mx[r] > m_r[r] + 8.f);
    const bool wgrow = __any(grow);
    if (wgrow){
      #pragma unroll
      for (int r = 0; r < 4; r++){
        float mn = fmaxf(m_r[r], mx[r]);
        alpha[r] = __expf(m_r[r] - mn);
        m_r[r] = mn;
      }
    } else {
      #pragma unroll
      for (int r = 0; r < 4; r++) alpha[r] = 1.f;
    }
    #pragma unroll
    for (int r = 0; r < 4; r++) l_r[r] *= alpha[r];

    float ps[4] = {0.f, 0.f, 0.f, 0.f};
    #pragma unroll
    for (int tf = 0; tf < 2; tf++)
      #pragma unroll
      for (int r = 0; r < 4; r++){
        float p = __expf(sc[tf][r] - m_r[r]);
        sc[tf][r] = p;
        ps[r] += p;
      }
    #pragma unroll
    for (int d = 1; d < 16; d <<= 1){
      #pragma unroll
      for (int r = 0; r < 4; r++) ps[r] += __shfl_xor(ps[r], d, 64);
    }
    #pragma unroll
    for (int r = 0; r < 4; r++) l_r[r] += ps[r];

    // ---- publish P, alpha, grow flag ----
    #pragma unroll
    for (int tf = 0; tf < 2; tf++)
      #pragma unroll
      for (int r = 0; r < 4; r++)
        Ps[w][g * 4 + r][tf * 16 + fr] = f2bf(sc[tf][r]);
    if (fr == 0){
      #pragma unroll
      for (int r = 0; r < 4; r++) Al[w][g * 4 + r] = alpha[r];
    }
    if (lane == 0) Fls[w] = wgrow ? 1 : 0;

    // ---- B2: publish Ps/Al/Fls + Vs[cur]; only V-waves drain vmcnt ----
    if (!isK) VM0;
    LGKM0; SBAR;

    // ---- split-D PV: wave w does cols w*64..+64 for ALL 128 rows ----
    int anyg = Fls[0] | Fls[1] | Fls[2] | Fls[3] | Fls[4] | Fls[5] | Fls[6] | Fls[7];

    short8 vf[4];
    #pragma unroll
    for (int hf = 0; hf < 4; hf++){
      int row = w * 64 + hf * 16 + fr;
      vf[hf] = *(const short8*)&Vs[cur][row * TB + ((g ^ ((row >> 1) & 3)) * 8)];
    }
    if (anyg){
      #pragma unroll
      for (int rw = 0; rw < 8; rw++){
        f32x4 alr = *(const f32x4*)&Al[rw][g * 4];
        #pragma unroll
        for (int hf = 0; hf < 4; hf++)
          #pragma unroll
          for (int r = 0; r < 4; r++) Oacc[rw][hf][r] *= alr[r];
      }
    }
    __builtin_amdgcn_s_setprio(1);
    #pragma unroll
    for (int rw = 0; rw < 8; rw++){
      short8 pa = *(const short8*)&Ps[rw][fr][g * 8];
      #pragma unroll
      for (int hf = 0; hf < 4; hf++)
        Oacc[rw][hf] = __builtin_amdgcn_mfma_f32_16x16x32_bf16(pa, vf[hf], Oacc[rw][hf], 0, 0, 0);
    }
    __builtin_amdgcn_s_setprio(0);

    // V-waves: issue next V tile (drained at B2 of t+1, a full half-tile away)
    if (t + 1 < t1 && !isK) stageV(cur ^ 1, t + 1);

    // ---- B1: publish Ks[cur^1]; only K-waves drain vmcnt ----
    if (isK) VM0;
    LGKM0; SBAR;
  }

  // ---- write bf16 partial O + (m,l) ----
  const long slot = (long)(bn * 16 + qi) * 3 + c;
  unsigned short* dst = Opart + slot * (QB * HH);
  #pragma unroll
  for (int rw = 0; rw < 8; rw++){
    #pragma unroll
    for (int hf = 0; hf < 4; hf++){
      int col = w * 64 + hf * 16 + fr;
      #pragma unroll
      for (int r = 0; r < 4; r++)
        dst[(rw * 16 + g * 4 + r) * HH + col] = f2bf(Oacc[rw][hf][r]);
    }
  }
  if (fr == 0){
    #pragma unroll
    for (int r = 0; r < 4; r++){
      int row = w * 16 + g * 4 + r;
      mlg[slot * 256 + row]       = m_r[r];
      mlg[slot * 256 + 128 + row] = l_r[r];
    }
  }
}

// ---------------- combine partials -> O (bf16) ----------------
__global__ __launch_bounds__(256) void k_combine(
    const unsigned short* __restrict__ Opart, const float* __restrict__ mlg,
    unsigned short* __restrict__ O, const int* __restrict__ maskedp)
{
  __shared__ float wl[128][3];
  const int gq = blockIdx.x;
  const int bn = gq & 7, qi = gq >> 3;
  const int b = bn >> 1, n = bn & 1;
  const int NC = (*maskedp) ? (4*qi + 25) / 22 : 2;
  const long slotbase = (long)(bn * 16 + qi) * 3;
  const int tid = threadIdx.x;

  if (tid < 128){
    float mc[3], lc[3];
    float M = -1e30f;
    for (int c = 0; c < NC; c++){
      mc[c] = mlg[(slotbase + c) * 256 + tid];
      lc[c] = mlg[(slotbase + c) * 256 + 128 + tid];
      M = fmaxf(M, mc[c]);
    }
    float L = 0.f;
    for (int c = 0; c < NC; c++){
      float wc = __expf(mc[c] - M);
      mc[c] = wc;
      L += lc[c] * wc;
    }
    float inv = 1.f / L;
    #pragma unroll
    for (int c = 0; c < 3; c++) wl[tid][c] = (c < NC) ? mc[c] * inv : 0.f;
  }
  __syncthreads();

  for (int it = 0; it < 32; it++){
    int idx = it * 256 + tid;                 // 128 rows x 64 chunks
    int row = idx >> 6, cv = idx & 63;
    float acc[8] = {0.f,0.f,0.f,0.f,0.f,0.f,0.f,0.f};
    for (int c = 0; c < NC; c++){
      float wc = wl[row][c];
      short8 v = *(const short8*)&Opart[(slotbase + c) * (QB * HH) + row * HH + cv * 8];
      #pragma unroll
      for (int j = 0; j < 8; j++){
        float f = __uint_as_float((unsigned)(unsigned short)v[j] << 16);
        acc[j] += f * wc;
      }
    }
    union { unsigned short u[8]; uint4 q; } rr;
    #pragma unroll
    for (int j = 0; j < 8; j++) rr.u[j] = f2bf(acc[j]);
    long dstoff = ((long)b * SS + qi * QB + row) * EE + n * HH + cv * 8;
    *(uint4*)&O[dstoff] = rr.q;
  }
}

// ---------------- host launch ----------------
extern "C" void kernel_launch(void* const* d_in, const int* in_sizes, int n_in,
                              void* d_out, int out_size, void* d_ws, size_t ws_size,
                              hipStream_t stream)
{
  const float* x   = (const float*)d_in[0];
  const float* Wq  = (const float*)d_in[1];
  const float* bq  = (const float*)d_in[2];
  const float* Wk  = (const float*)d_in[3];
  const float* bk  = (const float*)d_in[4];
  const float* Wv  = (const float*)d_in[5];
  const float* bv  = (const float*)d_in[6];
  const float* Wf  = (const float*)d_in[7];
  const float* bf_ = (const float*)d_in[8];
  const int* masked = (const int*)d_in[9];

  char* p = (char*)d_ws;
  const long TEN = (long)BB * SS * EE * 2;                 // 16 MiB per bf16 tensor
  unsigned short* xb  = (unsigned short*)p; p += TEN;      // x bf16, later reused as V^T
  unsigned short* Qb  = (unsigned short*)p; p += TEN;
  unsigned short* Kb  = (unsigned short*)p; p += TEN;
  unsigned short* Vb  = (unsigned short*)p; p += TEN;      // V, later reused as O
  unsigned short* wqb = (unsigned short*)p; p += 2L * HH * HH * 2;
  unsigned short* wkb = (unsigned short*)p; p += 2L * HH * HH * 2;
  unsigned short* wvb = (unsigned short*)p; p += 2L * HH * HH * 2;
  unsigned short* wfb = (unsigned short*)p; p += (long)EE * EE * 2;
  unsigned short* Opart = (unsigned short*)p; p += 384L * QB * HH * 2;   // 50 MB
  float* mlg = (float*)p; p += 384L * 256 * 4;                           // 0.4 MB

  k_cvt<<<dim3(2048), 256, 0, stream>>>(x,  xb,  BB * SS * EE / 8);
  k_cvt<<<dim3(256),  256, 0, stream>>>(Wq, wqb, 2 * HH * HH / 8);
  k_cvt<<<dim3(256),  256, 0, stream>>>(Wk, wkb, 2 * HH * HH / 8);
  k_cvt<<<dim3(256),  256, 0, stream>>>(Wv, wvb, 2 * HH * HH / 8);
  k_cvt<<<dim3(512),  256, 0, stream>>>(Wf, wfb, EE * EE / 8);

  k_qkv<<<dim3(SS / 128, HH / 128, 24), 256, 0, stream>>>(xb, wqb, wkb, wvb, bq, bk, bv, Qb, Kb, Vb);
  k_transpose<<<dim3(SS / 64, HH / 64, 8), 256, 0, stream>>>(Vb, xb);
  k_flash6<<<dim3(256), 512, 0, stream>>>(Qb, Kb, xb, Opart, mlg, masked);
  k_combine<<<dim3(128), 256, 0, stream>>>(Opart, mlg, Vb, masked);
  k_outproj<<<dim3((BB * SS) / 128, EE / 128, 1), 256, 0, stream>>>(Vb, wfb, bf_, (float*)d_out);
}

// Round 7
// 237.839 us; speedup vs baseline: 1.3337x; 1.3337x over previous
//
#include <hip/hip_runtime.h>
#include <hip/hip_bf16.h>

#define BB 4
#define SS 2048
#define EE 1024
#define HH 512

typedef __attribute__((ext_vector_type(8))) short short8;
typedef __attribute__((ext_vector_type(4))) float f32x4;
typedef __attribute__((ext_vector_type(16))) float f32x16;

static __device__ __forceinline__ unsigned short f2bf(float x){
  unsigned u = __float_as_uint(x);
  u += 0x7fffu + ((u >> 16) & 1u);
  return (unsigned short)(u >> 16);
}

static __device__ __forceinline__ unsigned cvtpk(float lo, float hi){
  unsigned d;
  asm("v_cvt_pk_bf16_f32 %0, %1, %2" : "=v"(d) : "v"(lo), "v"(hi));
  return d;
}

static __device__ __forceinline__ void gload16(const void* g, void* l){
  __builtin_amdgcn_global_load_lds((const __attribute__((address_space(1))) void*)g,
                                   (__attribute__((address_space(3))) void*)l, 16, 0, 0);
}

// ---------------- fp32 -> bf16 conversion (vectorized, grid-stride) ----------------
__global__ void k_cvt(const float* __restrict__ in, unsigned short* __restrict__ out, int n8){
  int idx = blockIdx.x * blockDim.x + threadIdx.x;
  int stride = gridDim.x * blockDim.x;
  for (int i = idx; i < n8; i += stride){
    const float4* p = (const float4*)in + (long)i * 2;
    float4 a = p[0], b = p[1];
    union { unsigned short u[8]; uint4 v; } r;
    r.u[0]=f2bf(a.x); r.u[1]=f2bf(a.y); r.u[2]=f2bf(a.z); r.u[3]=f2bf(a.w);
    r.u[4]=f2bf(b.x); r.u[5]=f2bf(b.y); r.u[6]=f2bf(b.z); r.u[7]=f2bf(b.w);
    ((uint4*)out)[i] = r.v;
  }
}

// ---------------- MFMA GEMM: C[M,N] = (A[M,K] * B^T + bias) * oscale ----------------
#define GBK 32

template<bool OUT_BF16>
static __device__ __forceinline__ void gemm_tile(
    const unsigned short* __restrict__ A, int lda,
    const unsigned short* __restrict__ Bw, int ldb,
    void* __restrict__ Cc, int ldc,
    const float* __restrict__ bias, int K, int row0, int col0, float oscale)
{
  __shared__ unsigned short As[2][128 * GBK];
  __shared__ unsigned short Bs[2][128 * GBK];
  const int tid = threadIdx.x, lane = tid & 63, w = tid >> 6;
  const int wm = w >> 1, wn = w & 1;
  const int fr = lane & 15, g = lane >> 4;

  f32x4 acc[4][4];
  #pragma unroll
  for (int i = 0; i < 4; i++)
    #pragma unroll
    for (int j = 0; j < 4; j++){ acc[i][j][0]=0.f; acc[i][j][1]=0.f; acc[i][j][2]=0.f; acc[i][j][3]=0.f; }

  const unsigned short* gAsrc[2]; const unsigned short* gBsrc[2];
  unsigned ldsOff[2];
  #pragma unroll
  for (int i = 0; i < 2; i++){
    int slot = w*128 + i*64 + lane;
    int row = slot >> 2, ch = slot & 3;
    int sc_ = ch ^ ((row >> 1) & 3);
    gAsrc[i] = A  + (long)(row0 + row) * lda + sc_ * 8;
    gBsrc[i] = Bw + (long)(col0 + row) * ldb + sc_ * 8;
    ldsOff[i] = (unsigned)((w*128 + i*64) * 8);
  }

  unsigned aoff[4], boff[4];
  #pragma unroll
  for (int mi = 0; mi < 4; mi++){
    int row = wm*64 + mi*16 + fr;
    aoff[mi] = row * GBK + ((g ^ ((row >> 1) & 3)) * 8);
  }
  #pragma unroll
  for (int ni = 0; ni < 4; ni++){
    int row = wn*64 + ni*16 + fr;
    boff[ni] = row * GBK + ((g ^ ((row >> 1) & 3)) * 8);
  }

  const int KT = K / GBK;
  #pragma unroll
  for (int i = 0; i < 2; i++) gload16(gAsrc[i], &As[0][ldsOff[i]]);
  #pragma unroll
  for (int i = 0; i < 2; i++) gload16(gBsrc[i], &Bs[0][ldsOff[i]]);
  __syncthreads();

  for (int kt = 0; kt < KT; ++kt){
    const int cur = kt & 1;
    if (kt + 1 < KT){
      #pragma unroll
      for (int i = 0; i < 2; i++) gload16(gAsrc[i] + (kt+1)*GBK, &As[cur^1][ldsOff[i]]);
      #pragma unroll
      for (int i = 0; i < 2; i++) gload16(gBsrc[i] + (kt+1)*GBK, &Bs[cur^1][ldsOff[i]]);
    }
    short8 av[4], bv[4];
    #pragma unroll
    for (int mi = 0; mi < 4; mi++) av[mi] = *(const short8*)&As[cur][aoff[mi]];
    #pragma unroll
    for (int ni = 0; ni < 4; ni++) bv[ni] = *(const short8*)&Bs[cur][boff[ni]];
    #pragma unroll
    for (int mi = 0; mi < 4; mi++)
      #pragma unroll
      for (int ni = 0; ni < 4; ni++)
        acc[mi][ni] = __builtin_amdgcn_mfma_f32_16x16x32_bf16(av[mi], bv[ni], acc[mi][ni], 0, 0, 0);
    __syncthreads();
  }

  #pragma unroll
  for (int mi = 0; mi < 4; mi++){
    #pragma unroll
    for (int ni = 0; ni < 4; ni++){
      int row = row0 + wm*64 + mi*16 + g*4;
      int col = col0 + wn*64 + ni*16 + fr;
      float bb = bias[col];
      #pragma unroll
      for (int r = 0; r < 4; r++){
        float v = (acc[mi][ni][r] + bb) * oscale;
        if (OUT_BF16) ((unsigned short*)Cc)[(long)(row + r) * ldc + col] = f2bf(v);
        else          ((float*)Cc)[(long)(row + r) * ldc + col] = v;
      }
    }
  }
}

__global__ __launch_bounds__(256, 2) void k_qkv(
    const unsigned short* __restrict__ xb,
    const unsigned short* __restrict__ wq, const unsigned short* __restrict__ wk,
    const unsigned short* __restrict__ wv,
    const float* __restrict__ bq, const float* __restrict__ bk, const float* __restrict__ bv,
    unsigned short* __restrict__ Q, unsigned short* __restrict__ K, unsigned short* __restrict__ V)
{
  int z = blockIdx.z; int which = z >> 3; int bn = z & 7; int b = bn >> 1, n = bn & 1;
  const unsigned short* W; const float* bias; unsigned short* out;
  float os = 1.f;
  if (which == 0){ W = wq; bias = bq; out = Q; os = 0.044194173824159216f; }  // fold 1/sqrt(512)
  else if (which == 1){ W = wk; bias = bk; out = K; }
  else { W = wv; bias = bv; out = V; }
  W += n * HH * HH; bias += n * HH; out += (long)bn * SS * HH;
  const unsigned short* Ap = xb + (long)b * SS * EE + n * HH;
  gemm_tile<true>(Ap, EE, W, HH, out, HH, bias, HH, blockIdx.x * 128, blockIdx.y * 128, os);
}

__global__ __launch_bounds__(256, 2) void k_outproj(
    const unsigned short* __restrict__ O, const unsigned short* __restrict__ wf,
    const float* __restrict__ bfb, float* __restrict__ out)
{
  gemm_tile<false>(O, EE, wf, EE, out, EE, bfb, EE, blockIdx.x * 128, blockIdx.y * 128, 1.f);
}

// ---------------- V [bn][s][o] -> Vt [bn][o][s] ----------------
__global__ __launch_bounds__(256) void k_transpose(const unsigned short* __restrict__ V,
                                                   unsigned short* __restrict__ Vt){
  __shared__ unsigned short t[64 * 64];
  long base = (long)blockIdx.z * SS * HH;
  const unsigned short* in = V + base;
  unsigned short* out = Vt + base;
  int s0 = blockIdx.x * 64, o0 = blockIdx.y * 64;
  int tid = threadIdx.x;
  int r = tid >> 3, cch = tid & 7;
  #pragma unroll
  for (int p = 0; p < 2; p++){
    int s = p * 32 + r;
    uint4 v = *(const uint4*)&in[(long)(s0 + s) * HH + o0 + cch * 8];
    *(uint4*)&t[s * 64 + ((cch ^ ((s >> 3) & 7)) * 8)] = v;
  }
  __syncthreads();
  #pragma unroll
  for (int p = 0; p < 2; p++){
    int o = p * 32 + r;
    union { unsigned short u[8]; uint4 v; } x;
    #pragma unroll
    for (int j = 0; j < 8; j++){
      int s = cch * 8 + j;
      x.u[j] = t[s * 64 + (((o >> 3) ^ ((s >> 3) & 7)) * 8) + (o & 7)];
    }
    *(uint4*)&out[(long)(o0 + o) * SS + s0 + cch * 8] = x.v;
  }
}

// ---------------- flash attention v7: 32-row waves, swapped QK, fp32 exchange ----------
// 8 waves (512 thr), QB=128: wave w -> rows rg=w&3 (32 q), K/D-half dh=w>>2.
// QK swapped (A=K, B=Q) over this wave's 256-dim K-half -> S^T[t][q], q=lane&31.
// Halves summed via fp32 LDS exchange (float2, b64). Softmax lane-local (1 shfl).
// P packed to MFMA A-frags in-register (cvt_pk + shfl_xor(32), verified mapping).
// PV: O[32 q][256 h] per wave. K dbuf, V single-buf; plain __syncthreads x2/tile.
#define QB 128
#define TB 32

__global__ __launch_bounds__(512, 1) void k_flash7(
    const unsigned short* __restrict__ Qg, const unsigned short* __restrict__ Kg,
    const unsigned short* __restrict__ Vtg,
    unsigned short* __restrict__ Opart, float* __restrict__ mlg,
    const int* __restrict__ maskedp)
{
  __shared__ unsigned short Ks[2][TB * HH];   // 64KB: [32 t][512 k], chunk swz: ch ^ (t&7)
  __shared__ unsigned short Vs[HH * TB];      // 32KB: [512 h][32 t], chunk swz: ch ^ ((h>>1)&3)
  __shared__ float2 Sx[4][2][8][64];          // 32KB: fp32 partial-score exchange

  const int bid = blockIdx.x;
  const int bn = bid & 7;                     // XCD pinning
  const int u = bid >> 3;
  const int masked = *maskedp;
  int qi, c;
  if (masked){
    qi = -1; c = 0;
    int cnt = 0;
    #pragma unroll 1
    for (int q = 0; q < 16; q++){
      int nch = (4*q + 25) / 22;              // ceil((4q+4)/22); sum = 32
      if (qi < 0 && u >= cnt && u < cnt + nch){ qi = q; c = u - cnt; }
      cnt += nch;
    }
    if (qi < 0) return;
  } else { qi = u >> 1; c = u & 1; }
  const int n  = masked ? 4*qi + 4 : 64;
  const int CH = masked ? 22 : 32;
  const int t0 = c * CH;
  const int t1 = min(n, t0 + CH);

  const long base = (long)bn * SS * HH;
  const unsigned short* Qp = Qg + base;
  const unsigned short* Kp = Kg + base;
  const unsigned short* Vp = Vtg + base;

  const int tid = threadIdx.x, lane = tid & 63, w = tid >> 6;
  const int ln = lane & 31, hi = lane >> 5;
  const int rg = w & 3, dh = w >> 2;
  const int q0 = qi * QB;
  const int myq = q0 + rg * 32 + ln;          // this lane's softmax row

  // Q as B-frags for this wave's K-half: Qr[ks] = Q[myq][dh*256 + ks*16 + hi*8 ..+8]
  short8 Qr[16];
  {
    const unsigned short* qrow = Qp + (long)myq * HH + dh * 256 + hi * 8;
    #pragma unroll
    for (int ks = 0; ks < 16; ks++) Qr[ks] = *(const short8*)(qrow + ks * 16);
  }

  f32x16 oa[8];
  #pragma unroll
  for (int i = 0; i < 8; i++)
    #pragma unroll
    for (int r = 0; r < 16; r++) oa[i][r] = 0.f;
  float m_r = -1e30f, l_r = 0.f;

  auto stageK = [&](int buf, int t){          // waves 0-3: K tile (32 rows x 64 chunks)
    if (w < 4){
      #pragma unroll
      for (int i = 0; i < 8; i++){
        const int sbase = w * 512 + i * 64;
        const int slot = sbase + lane;
        int row = slot >> 6, ch = slot & 63;
        int sc_ = ch ^ (row & 7);
        gload16(Kp + (long)(t * TB + row) * HH + sc_ * 8, &Ks[buf][sbase * 8]);
      }
    }
  };
  auto stageV = [&](int t){                   // waves 4-7: V^T tile (512 rows x 4 chunks)
    if (w >= 4){
      #pragma unroll
      for (int i = 0; i < 8; i++){
        const int sbase = (w - 4) * 512 + i * 64;
        const int slot = sbase + lane;
        int row = slot >> 2, ch = slot & 3;
        int sc_ = ch ^ ((row >> 1) & 3);
        gload16(Vp + (long)row * SS + t * TB + sc_ * 8, &Vs[sbase * 8]);
      }
    }
  };

  stageK(0, t0);
  stageV(t0);
  __syncthreads();

  for (int t = t0; t < t1; ++t){
    const int cur = (t - t0) & 1;
    if (t > t0)     stageV(t);                // Vs free (PV(t-1) done); drained at B1
    if (t + 1 < t1) stageK(cur ^ 1, t + 1);   // drained at B1 (over-drain, issued early)

    // ---- QK^T (swapped): partial S^T[t][q] over this wave's K-half ----
    f32x16 sa;
    #pragma unroll
    for (int r = 0; r < 16; r++) sa[r] = 0.f;
    #pragma unroll
    for (int ks = 0; ks < 16; ks++){
      int ch = (dh * 32 + ks * 2 + hi) ^ (ln & 7);
      short8 kf = *(const short8*)&Ks[cur][ln * HH + ch * 8];
      sa = __builtin_amdgcn_mfma_f32_32x32x16_bf16(kf, Qr[ks], sa, 0, 0, 0);
    }

    // ---- publish fp32 partials ----
    #pragma unroll
    for (int i = 0; i < 8; i++)
      Sx[rg][dh][i][lane] = make_float2(sa[2*i], sa[2*i+1]);

    __syncthreads();                          // B1: Sx + V(t) visible

    // ---- sum halves ----
    float p[16];
    #pragma unroll
    for (int i = 0; i < 8; i++){
      float2 o = Sx[rg][dh ^ 1][i][lane];
      p[2*i]   = sa[2*i]   + o.x;
      p[2*i+1] = sa[2*i+1] + o.y;
    }

    // ---- mask ----
    if (masked && (t * TB + TB - 1 > myq)){
      #pragma unroll
      for (int r = 0; r < 16; r++){
        int tl = (r & 3) + 8 * (r >> 2) + 4 * hi;
        if (t * TB + tl > myq) p[r] = -1e30f;
      }
    }

    // ---- lane-local softmax (row q = lane&31) ----
    float mx = p[0];
    #pragma unroll
    for (int r = 1; r < 16; r++) mx = fmaxf(mx, p[r]);
    mx = fmaxf(mx, __shfl_xor(mx, 32, 64));
    if (__any(mx > m_r + 8.f)){
      float mn = fmaxf(m_r, mx);
      float alpha = __expf(m_r - mn);
      m_r = mn; l_r *= alpha;
      #pragma unroll
      for (int r = 0; r < 16; r++){
        float al = __shfl(alpha, (r & 3) + 8 * (r >> 2) + 4 * hi, 64);
        #pragma unroll
        for (int i = 0; i < 8; i++) oa[i][r] *= al;
      }
    }
    float ps = 0.f;
    #pragma unroll
    for (int r = 0; r < 16; r++){ float pe = __expf(p[r] - m_r); p[r] = pe; ps += pe; }
    ps += __shfl_xor(ps, 32, 64);
    l_r += ps;

    // ---- T12 P-pack: build PV A-frags in-register (mapping verified) ----
    unsigned W[8], R[8];
    #pragma unroll
    for (int i = 0; i < 8; i++) W[i] = cvtpk(p[2*i], p[2*i+1]);
    #pragma unroll
    for (int i = 0; i < 8; i++) R[i] = __shfl_xor(W[i], 32, 64);
    union { unsigned u[4]; short8 s; } fa0, fa1;
    fa0.u[0] = hi ? R[2] : W[0];  fa0.u[1] = hi ? R[3] : W[1];
    fa0.u[2] = hi ? W[2] : R[0];  fa0.u[3] = hi ? W[3] : R[1];
    fa1.u[0] = hi ? R[6] : W[4];  fa1.u[1] = hi ? R[7] : W[5];
    fa1.u[2] = hi ? W[6] : R[4];  fa1.u[3] = hi ? W[7] : R[5];

    // ---- PV: O[32 q][256 h] += P[32 q][32 t] * Vt (this wave's D-half) ----
    #pragma unroll
    for (int cf = 0; cf < 8; cf++){
      int h = dh * 256 + cf * 32 + ln;
      int sw = (h >> 1) & 3;
      short8 v0 = *(const short8*)&Vs[h * TB + ((hi     ^ sw) * 8)];
      oa[cf] = __builtin_amdgcn_mfma_f32_32x32x16_bf16(fa0.s, v0, oa[cf], 0, 0, 0);
      short8 v1 = *(const short8*)&Vs[h * TB + (((2+hi) ^ sw) * 8)];
      oa[cf] = __builtin_amdgcn_mfma_f32_32x32x16_bf16(fa1.s, v1, oa[cf], 0, 0, 0);
    }

    __syncthreads();                          // B2: Vs/Sx free for next iter
  }

  // ---- write bf16 partial O + (m,l) ----
  const long slot = (long)(bn * 16 + qi) * 3 + c;
  unsigned short* dst = Opart + slot * (QB * HH);
  #pragma unroll
  for (int cf = 0; cf < 8; cf++){
    int col = dh * 256 + cf * 32 + ln;
    #pragma unroll
    for (int r = 0; r < 16; r++){
      int row = rg * 32 + (r & 3) + 8 * (r >> 2) + 4 * hi;
      dst[row * HH + col] = f2bf(oa[cf][r]);
    }
  }
  if (w < 4 && hi == 0){
    mlg[slot * 256 + rg * 32 + ln]       = m_r;
    mlg[slot * 256 + 128 + rg * 32 + ln] = l_r;
  }
}

// ---------------- combine partials -> O (bf16) ----------------
__global__ __launch_bounds__(256) void k_combine(
    const unsigned short* __restrict__ Opart, const float* __restrict__ mlg,
    unsigned short* __restrict__ O, const int* __restrict__ maskedp)
{
  __shared__ float wl[128][3];
  const int gq = blockIdx.x;
  const int bn = gq & 7, qi = gq >> 3;
  const int b = bn >> 1, n = bn & 1;
  const int NC = (*maskedp) ? (4*qi + 25) / 22 : 2;
  const long slotbase = (long)(bn * 16 + qi) * 3;
  const int tid = threadIdx.x;

  if (tid < 128){
    float mc[3], lc[3];
    float M = -1e30f;
    for (int c = 0; c < NC; c++){
      mc[c] = mlg[(slotbase + c) * 256 + tid];
      lc[c] = mlg[(slotbase + c) * 256 + 128 + tid];
      M = fmaxf(M, mc[c]);
    }
    float L = 0.f;
    for (int c = 0; c < NC; c++){
      float wc = __expf(mc[c] - M);
      mc[c] = wc;
      L += lc[c] * wc;
    }
    float inv = 1.f / L;
    #pragma unroll
    for (int c = 0; c < 3; c++) wl[tid][c] = (c < NC) ? mc[c] * inv : 0.f;
  }
  __syncthreads();

  for (int it = 0; it < 32; it++){
    int idx = it * 256 + tid;                 // 128 rows x 64 chunks
    int row = idx >> 6, cv = idx & 63;
    float acc[8] = {0.f,0.f,0.f,0.f,0.f,0.f,0.f,0.f};
    for (int c = 0; c < NC; c++){
      float wc = wl[row][c];
      short8 v = *(const short8*)&Opart[(slotbase + c) * (QB * HH) + row * HH + cv * 8];
      #pragma unroll
      for (int j = 0; j < 8; j++){
        float f = __uint_as_float((unsigned)(unsigned short)v[j] << 16);
        acc[j] += f * wc;
      }
    }
    union { unsigned short u[8]; uint4 q; } rr;
    #pragma unroll
    for (int j = 0; j < 8; j++) rr.u[j] = f2bf(acc[j]);
    long dstoff = ((long)b * SS + qi * QB + row) * EE + n * HH + cv * 8;
    *(uint4*)&O[dstoff] = rr.q;
  }
}

// ---------------- host launch ----------------
extern "C" void kernel_launch(void* const* d_in, const int* in_sizes, int n_in,
                              void* d_out, int out_size, void* d_ws, size_t ws_size,
                              hipStream_t stream)
{
  const float* x   = (const float*)d_in[0];
  const float* Wq  = (const float*)d_in[1];
  const float* bq  = (const float*)d_in[2];
  const float* Wk  = (const float*)d_in[3];
  const float* bk  = (const float*)d_in[4];
  const float* Wv  = (const float*)d_in[5];
  const float* bv  = (const float*)d_in[6];
  const float* Wf  = (const float*)d_in[7];
  const float* bf_ = (const float*)d_in[8];
  const int* masked = (const int*)d_in[9];

  char* p = (char*)d_ws;
  const long TEN = (long)BB * SS * EE * 2;                 // 16 MiB per bf16 tensor
  unsigned short* xb  = (unsigned short*)p; p += TEN;      // x bf16, later reused as V^T
  unsigned short* Qb  = (unsigned short*)p; p += TEN;
  unsigned short* Kb  = (unsigned short*)p; p += TEN;
  unsigned short* Vb  = (unsigned short*)p; p += TEN;      // V, later reused as O
  unsigned short* wqb = (unsigned short*)p; p += 2L * HH * HH * 2;
  unsigned short* wkb = (unsigned short*)p; p += 2L * HH * HH * 2;
  unsigned short* wvb = (unsigned short*)p; p += 2L * HH * HH * 2;
  unsigned short* wfb = (unsigned short*)p; p += (long)EE * EE * 2;
  unsigned short* Opart = (unsigned short*)p; p += 384L * QB * HH * 2;   // 50 MB
  float* mlg = (float*)p; p += 384L * 256 * 4;                           // 0.4 MB

  k_cvt<<<dim3(2048), 256, 0, stream>>>(x,  xb,  BB * SS * EE / 8);
  k_cvt<<<dim3(256),  256, 0, stream>>>(Wq, wqb, 2 * HH * HH / 8);
  k_cvt<<<dim3(256),  256, 0, stream>>>(Wk, wkb, 2 * HH * HH / 8);
  k_cvt<<<dim3(256),  256, 0, stream>>>(Wv, wvb, 2 * HH * HH / 8);
  k_cvt<<<dim3(512),  256, 0, stream>>>(Wf, wfb, EE * EE / 8);

  k_qkv<<<dim3(SS / 128, HH / 128, 24), 256, 0, stream>>>(xb, wqb, wkb, wvb, bq, bk, bv, Qb, Kb, Vb);
  k_transpose<<<dim3(SS / 64, HH / 64, 8), 256, 0, stream>>>(Vb, xb);
  k_flash7<<<dim3(256), 512, 0, stream>>>(Qb, Kb, xb, Opart, mlg, masked);
  k_combine<<<dim3(128), 256, 0, stream>>>(Opart, mlg, Vb, masked);
  k_outproj<<<dim3((BB * SS) / 128, EE / 128, 1), 256, 0, stream>>>(Vb, wfb, bf_, (float*)d_out);
}